// Round 11
// baseline (183.247 us; speedup 1.0000x reference)
//
#include <hip/hip_runtime.h>
#include <stdint.h>
#include <stddef.h>

typedef __attribute__((ext_vector_type(8))) short bf16x8;
typedef __attribute__((ext_vector_type(4))) float f32x4;
typedef __attribute__((ext_vector_type(4))) int i32x4;

#define NH 128
#define NW 128
#define NC 64
#define NF 256
#define SLOT 16384                 // one x-row image: [w=128][cb=8 x 16B], XOR-swizzled
#define XOFF 294912                // x images start here in ws (after 288 KB B table)
#define WS_NEED (XOFF + 2048 * SLOT)
#define NT 4                       // rows per strip block

__device__ __forceinline__ unsigned short f2b(float f) {
  union { float f; uint32_t u; } t; t.f = f;
  uint32_t u = t.u;
  return (unsigned short)((u + 0x7fffu + ((u >> 16) & 1u)) >> 16);
}

__device__ __forceinline__ void gload16(const void* g, void* l) {
  __builtin_amdgcn_global_load_lds(
      (const __attribute__((address_space(1))) unsigned int*)g,
      (__attribute__((address_space(3))) unsigned int*)l, 16, 0, 0);
}

// raw barrier: orders LDS ops across waves WITHOUT draining vmcnt (stores fly on)
#define EPI_BAR() do { \
  asm volatile("s_waitcnt lgkmcnt(0)" ::: "memory"); \
  __builtin_amdgcn_sched_barrier(0); \
  __builtin_amdgcn_s_barrier(); \
  __builtin_amdgcn_sched_barrier(0); } while (0)

// Combined prep (R8-verified, unchanged).
__global__ void prep_all(const float* __restrict__ x, const float* __restrict__ kr,
                         unsigned short* __restrict__ ws) {
  int bid = (int)blockIdx.x;
  if (bid < 72) {
    int t = bid * 256 + threadIdx.x;   // [0, 18432)
    int lane = t & 63;
    int kk   = (t >> 6) & 1;
    int cf   = (t >> 7) & 7;
    int rest = t >> 10;          // fi*9 + s
    int s  = rest % 9;
    int fi = rest / 9;
    int l15 = lane & 15, l4 = lane >> 4;
    int col = fi * 128 + cf * 16 + l15;
    int k0  = s * 64 + (kk * 4 + l4) * 8;
    unsigned short* dst = ws + (size_t)t * 8;
    const float* src = kr + (size_t)k0 * NF + col;
    #pragma unroll
    for (int e = 0; e < 8; ++e) dst[e] = f2b(src[(size_t)e * NF]);
  } else {
    int idx = (bid - 72) * 256 + threadIdx.x;   // [0, 2097152) 16B tasks
    int q   = idx & 1023;
    int row = idx >> 10;                        // b*128+h
    int w = q >> 3, cb = q & 7;
    const float* src = x + ((size_t)row * NW + w) * NC + cb * 8;
    float4 a0 = *(const float4*)(src);
    float4 a1 = *(const float4*)(src + 4);
    union { unsigned short u[8]; i32x4 v; } p;
    p.u[0] = f2b(a0.x); p.u[1] = f2b(a0.y); p.u[2] = f2b(a0.z); p.u[3] = f2b(a0.w);
    p.u[4] = f2b(a1.x); p.u[5] = f2b(a1.y); p.u[6] = f2b(a1.z); p.u[7] = f2b(a1.w);
    *(i32x4*)((char*)ws + XOFF + (size_t)row * SLOT + w * 128 + ((cb ^ (w & 7)) << 4)) = p.v;
  }
}

// Strip kernel: block = NT=4 consecutive h rows x half-N (128F). 4 waves,
// wave tile 64w x 64F per tile. Rolling 4-slot ring (slot = rel_row & 3) +
// dedicated 8 KB transpose buffer. Stores issue in an all-raw-barrier
// epilogue and drain under the NEXT tile's MFMA phase.
__global__ __launch_bounds__(256, 2)
void conv_strip(const unsigned short* __restrict__ bt,
                const float* __restrict__ bias, float* __restrict__ out)
{
  __shared__ __align__(16) char lds[4 * SLOT + 8192];   // 72 KB
  char* epi = lds + 4 * SLOT;

  const int tid  = threadIdx.x;
  const int lane = tid & 63;
  const int l15  = lane & 15;
  const int l4   = lane >> 4;
  const int wid  = tid >> 6;
  const int wm   = wid >> 1;    // w-half
  const int wn   = wid & 1;     // F-half of the fi half

  // XCD swizzle: 1024 blocks, 128/XCD, bijective.
  int bid  = (int)blockIdx.x;
  int work = (bid & 7) * 128 + (bid >> 3);
  int fi = work & 1;
  int hp = (work >> 1) & 31;
  int bb = work >> 6;
  int h0 = hp * NT;
  int F0 = fi * 128;

  const char* bimg = (const char*)bt + (size_t)fi * 9 * 16384;
  const int boff = (wn * 4) * 2048 + lane * 16;
  const char* xim = (const char*)bt + XOFF + (size_t)(bb * NH) * SLOT;

  // A-address LUT (R10-verified): addr(m,dwi) = slotb + ((trow+m*2048)&16383) + swz
  int trow[3], swz[3];
  #pragma unroll
  for (int dwi = 0; dwi < 3; ++dwi) {
    int t = l15 + 1 - dwi;
    trow[dwi] = ((wm * 64 + t) & 127) * 128;
    swz[dwi]  = (l4 ^ (t & 7)) << 4;
  }

  bf16x8 breg[2][4][2];

  // ---- prologue: B0->buf0, B1->buf1; DMA rows h0-1..h0+2 -> slots 3,0,1,2
  #pragma unroll
  for (int n = 0; n < 4; ++n)
    #pragma unroll
    for (int kk = 0; kk < 2; ++kk) {
      breg[0][n][kk] = *(const bf16x8*)(bimg + boff + n * 2048 + kk * 1024);
      breg[1][n][kk] = *(const bf16x8*)(bimg + 16384 + boff + n * 2048 + kk * 1024);
    }
  #pragma unroll
  for (int r = 0; r < 4; ++r) {               // rel rows -1..2
    int xr = (h0 + r + 127) & 127;
    const char* src = xim + (size_t)xr * SLOT;
    char* dst = lds + ((r + 3) & 3) * SLOT;   // rel (r-1) & 3
    #pragma unroll
    for (int i = 0; i < 4; ++i) {
      int byte = tid * 16 + i * 4096;
      gload16(src + byte, dst + byte);
    }
  }
  float bv[4];
  #pragma unroll
  for (int n = 0; n < 4; ++n) bv[n] = bias[F0 + wn * 64 + n * 16 + l15];
  __syncthreads();     // drains prologue DMA + B0/B1

  #pragma unroll 1
  for (int j = 0; j < NT; ++j) {
    // slot bases: shift s reads rel row (j+1 - s%3)
    int sA[3];
    sA[0] = ((j + 1) & 3) * SLOT;
    sA[1] = (j & 3) * SLOT;
    sA[2] = ((j + 3) & 3) * SLOT;

    f32x4 acc[4][4];
    #pragma unroll
    for (int m = 0; m < 4; ++m)
      #pragma unroll
      for (int n = 0; n < 4; ++n)
        acc[m][n] = (f32x4){0.f, 0.f, 0.f, 0.f};

    // ---- compute: 9 shifts, pure ds_read + MFMA + B-prefetch ----
    #pragma unroll
    for (int s = 0; s < 9; ++s) {
      if (s >= 1 && s < 8) {   // prefetch B(s+1); s=0 skipped (buf1=B1 preloaded)
        const char* bs = bimg + (size_t)(s + 1) * 16384 + boff;
        #pragma unroll
        for (int n = 0; n < 4; ++n)
          #pragma unroll
          for (int kk = 0; kk < 2; ++kk)
            breg[(s + 1) & 1][n][kk] = *(const bf16x8*)(bs + n * 2048 + kk * 1024);
      }
      const int dwi   = s / 3;            // static
      const int slotb = sA[s % 3];        // static index
      #pragma unroll
      for (int kk = 0; kk < 2; ++kk) {
        bf16x8 af[4];
        #pragma unroll
        for (int m = 0; m < 4; ++m) {
          int addr = slotb + ((trow[dwi] + m * 2048) & 16383) + swz[dwi];
          af[m] = *(const bf16x8*)(lds + (addr ^ (kk << 6)));
        }
        #pragma unroll
        for (int m = 0; m < 4; ++m)
          #pragma unroll
          for (int n = 0; n < 4; ++n)
            acc[m][n] = __builtin_amdgcn_mfma_f32_16x16x32_bf16(
                af[m], breg[s & 1][n][kk], acc[m][n], 0, 0, 0);
      }
    }

    // Real barrier: drains prior-epilogue DMA/stores (all >= 1 phase old,
    // cheap) and fences this tile's LDS reads before ring-slot overwrite.
    __syncthreads();

    // ---- epilogue (raw barriers only; stores drain under next tile) ----
    if (j <= NT - 3) {   // DMA rel row j+3 -> slot (j+3)&3 (read from tile j+2 on)
      int xr = (h0 + j + 3) & 127;
      const char* src = xim + (size_t)xr * SLOT;
      char* dst = lds + ((j + 3) & 3) * SLOT;
      #pragma unroll
      for (int i = 0; i < 4; ++i) {
        int byte = tid * 16 + i * 4096;
        gload16(src + byte, dst + byte);
      }
    }
    if (j < NT - 1) {    // reload B0,B1 for next tile (consumed at its s=0/1)
      #pragma unroll
      for (int n = 0; n < 4; ++n)
        #pragma unroll
        for (int kk = 0; kk < 2; ++kk) {
          breg[0][n][kk] = *(const bf16x8*)(bimg + boff + n * 2048 + kk * 1024);
          breg[1][n][kk] = *(const bf16x8*)(bimg + 16384 + boff + n * 2048 + kk * 1024);
        }
    }

    size_t orow = ((size_t)(bb * NH + h0 + j) * NW) * NF + F0;
    float* eb = (float*)epi;   // [16][128] f32, rotation-swizzled
    #pragma unroll
    for (int p = 0; p < 8; ++p) {          // piece = 16 w-rows x 128 F
      if (wm == (p >> 2)) {                // owning wave-pair deposits m = p&3
        const int m = p & 3;
        #pragma unroll
        for (int jj = 0; jj < 4; ++jj) {
          int r16 = l4 * 4 + jj;
          int rot = (r16 & 7) << 2;
          #pragma unroll
          for (int n = 0; n < 4; ++n) {
            int c = wn * 64 + n * 16 + l15;
            eb[r16 * 128 + ((c + rot) & 127)] = acc[m][n][jj] + bv[n];
          }
        }
      }
      EPI_BAR();
      #pragma unroll
      for (int i = 0; i < 2; ++i) {        // all waves read+store full lines
        int r16 = i * 8 + (tid >> 5);
        int rot = (r16 & 7) << 2;
        int c4  = (tid & 31) * 4;
        f32x4 v = *(const f32x4*)(eb + r16 * 128 + ((c4 + rot) & 127));
        *(f32x4*)(out + orow + (size_t)(p * 16 + r16) * NF + c4) = v;
      }
      EPI_BAR();
    }
  }
}

// Fallback (ws too small): R10's verified single-tile kernel, non-DMA staging.
__global__ __launch_bounds__(256, 2)
void conv_single(const float* __restrict__ x, const unsigned short* __restrict__ bt,
                 const float* __restrict__ bias, float* __restrict__ out)
{
  __shared__ __align__(16) char lds[3 * SLOT];
  const int tid  = threadIdx.x;
  const int lane = tid & 63;
  const int l15  = lane & 15;
  const int l4   = lane >> 4;
  const int wid  = tid >> 6;
  const int wm   = wid >> 1;
  const int wn   = wid & 1;
  int bid  = (int)blockIdx.x;
  int work = (bid & 7) * 512 + (bid >> 3);
  int mi = work >> 1;
  int fi = work & 1;
  int bb = mi >> 7;
  int hh = mi & 127;
  int F0 = fi * 128;
  const char* bimg = (const char*)bt + (size_t)fi * 9 * 16384;
  const int boff = (wn * 4) * 2048 + lane * 16;
  bf16x8 breg[2][4][2];
  #pragma unroll
  for (int n = 0; n < 4; ++n)
    #pragma unroll
    for (int kk = 0; kk < 2; ++kk)
      breg[0][n][kk] = *(const bf16x8*)(bimg + boff + n * 2048 + kk * 1024);
  #pragma unroll
  for (int i = 0; i < 12; ++i) {
    int idx = tid + i * 256;
    int cb = idx & 7;
    int w  = (idx >> 3) & 127;
    int r  = idx >> 10;
    int xr = (hh + r + 127) & 127;
    const float* src = x + (((size_t)(bb * NH + xr) * NW + w) * NC + cb * 8);
    float4 a0 = *(const float4*)(src);
    float4 a1 = *(const float4*)(src + 4);
    union { unsigned short u[8]; i32x4 v; } p;
    p.u[0] = f2b(a0.x); p.u[1] = f2b(a0.y); p.u[2] = f2b(a0.z); p.u[3] = f2b(a0.w);
    p.u[4] = f2b(a1.x); p.u[5] = f2b(a1.y); p.u[6] = f2b(a1.z); p.u[7] = f2b(a1.w);
    *(i32x4*)(lds + (r * SLOT + w * 128 + ((cb ^ (w & 7)) << 4))) = p.v;
  }
  __syncthreads();
  int trow[3], swz[3];
  #pragma unroll
  for (int dwi = 0; dwi < 3; ++dwi) {
    int t = l15 + 1 - dwi;
    trow[dwi] = ((wm * 64 + t) & 127) * 128;
    swz[dwi]  = (l4 ^ (t & 7)) << 4;
  }
  f32x4 acc[4][4];
  #pragma unroll
  for (int m = 0; m < 4; ++m)
    #pragma unroll
    for (int n = 0; n < 4; ++n)
      acc[m][n] = (f32x4){0.f, 0.f, 0.f, 0.f};
  #pragma unroll
  for (int s = 0; s < 9; ++s) {
    if (s < 8) {
      const char* bs = bimg + (size_t)(s + 1) * 16384 + boff;
      #pragma unroll
      for (int n = 0; n < 4; ++n)
        #pragma unroll
        for (int kk = 0; kk < 2; ++kk)
          breg[(s + 1) & 1][n][kk] = *(const bf16x8*)(bs + n * 2048 + kk * 1024);
    }
    const int dwi   = s / 3;
    const int slotb = (2 - (s % 3)) * SLOT;
    #pragma unroll
    for (int kk = 0; kk < 2; ++kk) {
      bf16x8 af[4];
      #pragma unroll
      for (int m = 0; m < 4; ++m) {
        int addr = slotb + ((trow[dwi] + m * 2048) & 16383) + swz[dwi];
        af[m] = *(const bf16x8*)(lds + (addr ^ (kk << 6)));
      }
      #pragma unroll
      for (int m = 0; m < 4; ++m)
        #pragma unroll
        for (int n = 0; n < 4; ++n)
          acc[m][n] = __builtin_amdgcn_mfma_f32_16x16x32_bf16(
              af[m], breg[s & 1][n][kk], acc[m][n], 0, 0, 0);
    }
  }
  float bv[4];
  #pragma unroll
  for (int n = 0; n < 4; ++n) bv[n] = bias[F0 + wn * 64 + n * 16 + l15];
  __syncthreads();
  float* eb = (float*)lds;
  #pragma unroll
  for (int chunk = 0; chunk < 2; ++chunk) {
    if (wm == chunk) {
      #pragma unroll
      for (int m = 0; m < 4; ++m)
        #pragma unroll
        for (int jj = 0; jj < 4; ++jj) {
          int r = m * 16 + l4 * 4 + jj;
          #pragma unroll
          for (int n = 0; n < 4; ++n)
            eb[r * 132 + wn * 64 + n * 16 + l15] = acc[m][n][jj] + bv[n];
        }
    }
    __syncthreads();
    size_t obase = ((size_t)mi * 128 + chunk * 64) * NF + F0;
    #pragma unroll
    for (int i = 0; i < 8; ++i) {
      int r = i * 8 + wid * 2 + (lane >> 5);
      int c = (lane & 31) * 4;
      f32x4 v = *(const f32x4*)(eb + r * 132 + c);
      *(f32x4*)(out + obase + (size_t)r * NF + c) = v;
    }
    if (chunk == 0) __syncthreads();
  }
}

extern "C" void kernel_launch(void* const* d_in, const int* in_sizes, int n_in,
                              void* d_out, int out_size, void* d_ws, size_t ws_size,
                              hipStream_t stream) {
  const float* x    = (const float*)d_in[0];
  const float* kern = (const float*)d_in[1];
  const float* bias = (const float*)d_in[2];
  float* out = (float*)d_out;
  unsigned short* bt = (unsigned short*)d_ws;

  if (ws_size >= (size_t)WS_NEED) {
    prep_all<<<dim3(72 + 8192), dim3(256), 0, stream>>>(x, kern, bt);
    conv_strip<<<dim3(1024), dim3(256), 0, stream>>>(bt, bias, out);
  } else {
    prep_all<<<dim3(72), dim3(256), 0, stream>>>(x, kern, bt);
    conv_single<<<dim3(4096), dim3(256), 0, stream>>>(x, bt, bias, out);
  }
}

// Round 12
// 121.252 us; speedup vs baseline: 1.5113x; 1.5113x over previous
//
#include <hip/hip_runtime.h>
#include <stdint.h>
#include <stddef.h>

typedef __attribute__((ext_vector_type(8))) short bf16x8;
typedef __attribute__((ext_vector_type(4))) float f32x4;
typedef __attribute__((ext_vector_type(4))) int i32x4;

#define NH 128
#define NW 128
#define NC 64
#define NF 256
#define SLOT 16384                 // one x-row image: [w=128][cb=8 x 16B], XOR-swizzled
#define XOFF 294912                // x images start here in ws (after 288 KB B table)
#define WS_NEED (XOFF + 2048 * SLOT)
#define EPIB (3 * SLOT)            // epi buffer offset in LDS

__device__ __forceinline__ unsigned short f2b(float f) {
  union { float f; uint32_t u; } t; t.f = f;
  uint32_t u = t.u;
  return (unsigned short)((u + 0x7fffu + ((u >> 16) & 1u)) >> 16);
}

__device__ __forceinline__ void gload16(const void* g, void* l) {
  __builtin_amdgcn_global_load_lds(
      (const __attribute__((address_space(1))) unsigned int*)g,
      (__attribute__((address_space(3))) unsigned int*)l, 16, 0, 0);
}

// raw barrier: orders LDS ops across waves WITHOUT draining vmcnt
// (stores/DMA keep flying). Correctness-verified in R11.
#define EPI_BAR() do { \
  asm volatile("s_waitcnt lgkmcnt(0)" ::: "memory"); \
  __builtin_amdgcn_sched_barrier(0); \
  __builtin_amdgcn_s_barrier(); \
  __builtin_amdgcn_sched_barrier(0); } while (0)

// Combined prep (R8-verified, unchanged):
//  blocks [0,72):   B table in per-wave fragment order:
//    u16 elem ((fi*9+s)*16 + cf*2 + kk)*512 + lane*8 + e
//      = kern[(s*64 + (kk*4+(lane>>4))*8 + e)*NF + fi*128 + cf*16 + (lane&15)]
//  blocks [72,...): x -> bf16 swizzled 16KB row-images at XOFF:
//    image (b*128+h), byte w*128 + ((cb^(w&7))<<4) = x[b,h,w,cb*8..+8]
__global__ void prep_all(const float* __restrict__ x, const float* __restrict__ kr,
                         unsigned short* __restrict__ ws) {
  int bid = (int)blockIdx.x;
  if (bid < 72) {
    int t = bid * 256 + threadIdx.x;   // [0, 18432)
    int lane = t & 63;
    int kk   = (t >> 6) & 1;
    int cf   = (t >> 7) & 7;
    int rest = t >> 10;          // fi*9 + s
    int s  = rest % 9;
    int fi = rest / 9;
    int l15 = lane & 15, l4 = lane >> 4;
    int col = fi * 128 + cf * 16 + l15;
    int k0  = s * 64 + (kk * 4 + l4) * 8;
    unsigned short* dst = ws + (size_t)t * 8;
    const float* src = kr + (size_t)k0 * NF + col;
    #pragma unroll
    for (int e = 0; e < 8; ++e) dst[e] = f2b(src[(size_t)e * NF]);
  } else {
    int idx = (bid - 72) * 256 + threadIdx.x;   // [0, 2097152) 16B tasks
    int q   = idx & 1023;
    int row = idx >> 10;                        // b*128+h
    int w = q >> 3, cb = q & 7;
    const float* src = x + ((size_t)row * NW + w) * NC + cb * 8;
    float4 a0 = *(const float4*)(src);
    float4 a1 = *(const float4*)(src + 4);
    union { unsigned short u[8]; i32x4 v; } p;
    p.u[0] = f2b(a0.x); p.u[1] = f2b(a0.y); p.u[2] = f2b(a0.z); p.u[3] = f2b(a0.w);
    p.u[4] = f2b(a1.x); p.u[5] = f2b(a1.y); p.u[6] = f2b(a1.z); p.u[7] = f2b(a1.w);
    *(i32x4*)((char*)ws + XOFF + (size_t)row * SLOT + w * 128 + ((cb ^ (w & 7)) << 4)) = p.v;
  }
}

// fi-pair kernel: block = one (b,h), BOTH 128F halves sequentially.
// A staged once (DMA, 48 KB) and reused by both halves. fi=0's stores
// drain under fi=1's whole MFMA phase (epilogue uses raw barriers only —
// no vmcnt(0) drain anywhere after the prologue syncthreads).
__global__ __launch_bounds__(256, 2)
void conv_pair(const unsigned short* __restrict__ bt,
               const float* __restrict__ bias, float* __restrict__ out)
{
  __shared__ __align__(16) char lds[3 * SLOT + 16640];   // 64.25 KB
  float* eb = (float*)(lds + EPIB);   // [32][130] f32 transpose buffer

  const int tid  = threadIdx.x;
  const int lane = tid & 63;
  const int l15  = lane & 15;
  const int l4   = lane >> 4;
  const int wid  = tid >> 6;
  const int wm   = wid >> 1;    // w-half
  const int wn   = wid & 1;     // F-half within the fi half

  // XCD swizzle: 2048 blocks, 256 per XCD, bijective.
  int bid = (int)blockIdx.x;
  int mi  = (bid & 7) * 256 + (bid >> 3);   // (b,h) flat
  int bb  = mi >> 7;
  int hh  = mi & 127;

  const char* xim = (const char*)bt + XOFF;
  const int boff = (wn * 4) * 2048 + lane * 16;

  // A-address LUT (R10-verified): addr(m,dwi) = slotb + ((trow+m*2048)&16383) + swz
  int trow[3], swz[3];
  #pragma unroll
  for (int dwi = 0; dwi < 3; ++dwi) {
    int t = l15 + 1 - dwi;
    trow[dwi] = ((wm * 64 + t) & 127) * 128;
    swz[dwi]  = (l4 ^ (t & 7)) << 4;
  }

  bf16x8 breg[2][4][2];

  // ---- prologue: B(fi=0,s=0/1) + DMA A rows hh-1..hh+1 -> slots 0..2 ----
  #pragma unroll
  for (int n = 0; n < 4; ++n)
    #pragma unroll
    for (int kk = 0; kk < 2; ++kk) {
      breg[0][n][kk] = *(const bf16x8*)((const char*)bt + boff + n * 2048 + kk * 1024);
      breg[1][n][kk] = *(const bf16x8*)((const char*)bt + 16384 + boff + n * 2048 + kk * 1024);
    }
  #pragma unroll
  for (int r = 0; r < 3; ++r) {
    int xr = (hh + r + 127) & 127;
    const char* src = xim + (size_t)(bb * NH + xr) * SLOT;
    #pragma unroll
    for (int i = 0; i < 4; ++i) {
      int byte = tid * 16 + i * 4096;
      gload16(src + byte, lds + r * SLOT + byte);
    }
  }
  __syncthreads();   // the ONLY vmcnt-draining barrier (A-DMA must land)

  #pragma unroll
  for (int fi = 0; fi < 2; ++fi) {
    const char* bimg = (const char*)bt + (size_t)fi * 9 * 16384;

    f32x4 acc[4][4];
    #pragma unroll
    for (int m = 0; m < 4; ++m)
      #pragma unroll
      for (int n = 0; n < 4; ++n)
        acc[m][n] = (f32x4){0.f, 0.f, 0.f, 0.f};

    // ---- compute: 9 shifts, B dbuf (buf0=B0, buf1=B1 preloaded) ----
    #pragma unroll
    for (int s = 0; s < 9; ++s) {
      if (s >= 1 && s < 8) {   // prefetch B(fi,s+1) -> buffer (s+1)&1
        const char* bs = bimg + (size_t)(s + 1) * 16384 + boff;
        #pragma unroll
        for (int n = 0; n < 4; ++n)
          #pragma unroll
          for (int kk = 0; kk < 2; ++kk)
            breg[(s + 1) & 1][n][kk] = *(const bf16x8*)(bs + n * 2048 + kk * 1024);
      }
      const int dwi   = s / 3;                  // static
      const int slotb = (2 - (s % 3)) * SLOT;   // static
      #pragma unroll
      for (int kk = 0; kk < 2; ++kk) {
        bf16x8 af[4];
        #pragma unroll
        for (int m = 0; m < 4; ++m) {
          int addr = slotb + ((trow[dwi] + m * 2048) & 16383) + swz[dwi];
          af[m] = *(const bf16x8*)(lds + (addr ^ (kk << 6)));
        }
        #pragma unroll
        for (int m = 0; m < 4; ++m)
          #pragma unroll
          for (int n = 0; n < 4; ++n)
            acc[m][n] = __builtin_amdgcn_mfma_f32_16x16x32_bf16(
                af[m], breg[s & 1][n][kk], acc[m][n], 0, 0, 0);
      }
    }

    if (fi == 0) {   // issue fi=1's B0/B1 now: fly under the whole epilogue
      #pragma unroll
      for (int n = 0; n < 4; ++n)
        #pragma unroll
        for (int kk = 0; kk < 2; ++kk) {
          breg[0][n][kk] = *(const bf16x8*)((const char*)bt + 9 * 16384 + boff + n * 2048 + kk * 1024);
          breg[1][n][kk] = *(const bf16x8*)((const char*)bt + 10 * 16384 + boff + n * 2048 + kk * 1024);
        }
    }

    float bv[4];
    #pragma unroll
    for (int n = 0; n < 4; ++n) bv[n] = bias[fi * 128 + wn * 64 + n * 16 + l15];

    // ---- epilogue: 4 chunks x 32 w-rows, raw barriers only ----
    size_t ob0 = ((size_t)mi * NW) * NF + fi * 128;
    #pragma unroll
    for (int c = 0; c < 4; ++c) {
      if (wm == (c >> 1)) {            // owning wave-pair deposits
        #pragma unroll
        for (int mm = 0; mm < 2; ++mm) {
          const int m = (c & 1) * 2 + mm;
          #pragma unroll
          for (int jj = 0; jj < 4; ++jj) {
            int r = mm * 16 + l4 * 4 + jj;      // 0..31 chunk-local
            #pragma unroll
            for (int n = 0; n < 4; ++n)
              eb[r * 130 + wn * 64 + n * 16 + l15] = acc[m][n][jj] + bv[n];
          }
        }
      }
      EPI_BAR();
      #pragma unroll
      for (int p = 0; p < 4; ++p) {    // all waves: full-line f32x4 stores
        int r  = p * 8 + (tid >> 5);   // 0..31
        int c4 = (tid & 31) * 4;       // 0..124
        f32x4 v = *(const f32x4*)(eb + r * 130 + c4);
        *(f32x4*)(out + ob0 + (size_t)(c * 32 + r) * NF + c4) = v;
      }
      EPI_BAR();   // reads done before next deposit overwrites eb
    }
  }
}

// Fallback (ws too small): R10-verified single-tile kernel, direct staging.
__global__ __launch_bounds__(256, 2)
void conv_single(const float* __restrict__ x, const unsigned short* __restrict__ bt,
                 const float* __restrict__ bias, float* __restrict__ out)
{
  __shared__ __align__(16) char lds[3 * SLOT];
  const int tid  = threadIdx.x;
  const int lane = tid & 63;
  const int l15  = lane & 15;
  const int l4   = lane >> 4;
  const int wid  = tid >> 6;
  const int wm   = wid >> 1;
  const int wn   = wid & 1;
  int bid  = (int)blockIdx.x;
  int work = (bid & 7) * 512 + (bid >> 3);
  int mi = work >> 1;
  int fi = work & 1;
  int bb = mi >> 7;
  int hh = mi & 127;
  int F0 = fi * 128;
  const char* bimg = (const char*)bt + (size_t)fi * 9 * 16384;
  const int boff = (wn * 4) * 2048 + lane * 16;
  bf16x8 breg[2][4][2];
  #pragma unroll
  for (int n = 0; n < 4; ++n)
    #pragma unroll
    for (int kk = 0; kk < 2; ++kk)
      breg[0][n][kk] = *(const bf16x8*)(bimg + boff + n * 2048 + kk * 1024);
  #pragma unroll
  for (int i = 0; i < 12; ++i) {
    int idx = tid + i * 256;
    int cb = idx & 7;
    int w  = (idx >> 3) & 127;
    int r  = idx >> 10;
    int xr = (hh + r + 127) & 127;
    const float* src = x + (((size_t)(bb * NH + xr) * NW + w) * NC + cb * 8);
    float4 a0 = *(const float4*)(src);
    float4 a1 = *(const float4*)(src + 4);
    union { unsigned short u[8]; i32x4 v; } p;
    p.u[0] = f2b(a0.x); p.u[1] = f2b(a0.y); p.u[2] = f2b(a0.z); p.u[3] = f2b(a0.w);
    p.u[4] = f2b(a1.x); p.u[5] = f2b(a1.y); p.u[6] = f2b(a1.z); p.u[7] = f2b(a1.w);
    *(i32x4*)(lds + (r * SLOT + w * 128 + ((cb ^ (w & 7)) << 4))) = p.v;
  }
  __syncthreads();
  int trow[3], swz[3];
  #pragma unroll
  for (int dwi = 0; dwi < 3; ++dwi) {
    int t = l15 + 1 - dwi;
    trow[dwi] = ((wm * 64 + t) & 127) * 128;
    swz[dwi]  = (l4 ^ (t & 7)) << 4;
  }
  f32x4 acc[4][4];
  #pragma unroll
  for (int m = 0; m < 4; ++m)
    #pragma unroll
    for (int n = 0; n < 4; ++n)
      acc[m][n] = (f32x4){0.f, 0.f, 0.f, 0.f};
  #pragma unroll
  for (int s = 0; s < 9; ++s) {
    if (s < 8) {
      const char* bs = bimg + (size_t)(s + 1) * 16384 + boff;
      #pragma unroll
      for (int n = 0; n < 4; ++n)
        #pragma unroll
        for (int kk = 0; kk < 2; ++kk)
          breg[(s + 1) & 1][n][kk] = *(const bf16x8*)(bs + n * 2048 + kk * 1024);
    }
    const int dwi   = s / 3;
    const int slotb = (2 - (s % 3)) * SLOT;
    #pragma unroll
    for (int kk = 0; kk < 2; ++kk) {
      bf16x8 af[4];
      #pragma unroll
      for (int m = 0; m < 4; ++m) {
        int addr = slotb + ((trow[dwi] + m * 2048) & 16383) + swz[dwi];
        af[m] = *(const bf16x8*)(lds + (addr ^ (kk << 6)));
      }
      #pragma unroll
      for (int m = 0; m < 4; ++m)
        #pragma unroll
        for (int n = 0; n < 4; ++n)
          acc[m][n] = __builtin_amdgcn_mfma_f32_16x16x32_bf16(
              af[m], breg[s & 1][n][kk], acc[m][n], 0, 0, 0);
    }
  }
  float bv[4];
  #pragma unroll
  for (int n = 0; n < 4; ++n) bv[n] = bias[F0 + wn * 64 + n * 16 + l15];
  __syncthreads();
  float* eb = (float*)lds;
  #pragma unroll
  for (int chunk = 0; chunk < 2; ++chunk) {
    if (wm == chunk) {
      #pragma unroll
      for (int m = 0; m < 4; ++m)
        #pragma unroll
        for (int jj = 0; jj < 4; ++jj) {
          int r = m * 16 + l4 * 4 + jj;
          #pragma unroll
          for (int n = 0; n < 4; ++n)
            eb[r * 132 + wn * 64 + n * 16 + l15] = acc[m][n][jj] + bv[n];
        }
    }
    __syncthreads();
    size_t obase = ((size_t)mi * 128 + chunk * 64) * NF + F0;
    #pragma unroll
    for (int i = 0; i < 8; ++i) {
      int r = i * 8 + wid * 2 + (lane >> 5);
      int c = (lane & 31) * 4;
      f32x4 v = *(const f32x4*)(eb + r * 132 + c);
      *(f32x4*)(out + obase + (size_t)r * NF + c) = v;
    }
    if (chunk == 0) __syncthreads();
  }
}

extern "C" void kernel_launch(void* const* d_in, const int* in_sizes, int n_in,
                              void* d_out, int out_size, void* d_ws, size_t ws_size,
                              hipStream_t stream) {
  const float* x    = (const float*)d_in[0];
  const float* kern = (const float*)d_in[1];
  const float* bias = (const float*)d_in[2];
  float* out = (float*)d_out;
  unsigned short* bt = (unsigned short*)d_ws;

  if (ws_size >= (size_t)WS_NEED) {
    prep_all<<<dim3(72 + 8192), dim3(256), 0, stream>>>(x, kern, bt);
    conv_pair<<<dim3(2048), dim3(256), 0, stream>>>(bt, bias, out);
  } else {
    prep_all<<<dim3(72), dim3(256), 0, stream>>>(x, kern, bt);
    conv_single<<<dim3(4096), dim3(256), 0, stream>>>(x, bt, bias, out);
  }
}

// Round 13
// 111.567 us; speedup vs baseline: 1.6425x; 1.0868x over previous
//
#include <hip/hip_runtime.h>
#include <stdint.h>
#include <stddef.h>

typedef __attribute__((ext_vector_type(8))) short bf16x8;
typedef __attribute__((ext_vector_type(4))) float f32x4;
typedef __attribute__((ext_vector_type(4))) int i32x4;

#define NH 128
#define NW 128
#define NC 64
#define NF 256
#define SLOT 16384                 // one x-row image: [w=128][cb=8 x 16B], XOR-swizzled
#define XOFF 294912                // x images start here in ws (after 288 KB B table)
#define WS_NEED (XOFF + 2048 * SLOT)

__device__ __forceinline__ unsigned short f2b(float f) {
  union { float f; uint32_t u; } t; t.f = f;
  uint32_t u = t.u;
  return (unsigned short)((u + 0x7fffu + ((u >> 16) & 1u)) >> 16);
}

__device__ __forceinline__ void gload16(const void* g, void* l) {
  __builtin_amdgcn_global_load_lds(
      (const __attribute__((address_space(1))) unsigned int*)g,
      (__attribute__((address_space(3))) unsigned int*)l, 16, 0, 0);
}

// Combined prep (R8-verified, unchanged):
//  blocks [0,72):   B table in per-wave fragment order:
//    u16 elem ((fi*9+s)*16 + cf*2 + kk)*512 + lane*8 + e
//      = kern[(s*64 + (kk*4+(lane>>4))*8 + e)*NF + fi*128 + cf*16 + (lane&15)]
//  blocks [72,...): x -> bf16 swizzled 16KB row-images at XOFF:
//    image (b*128+h), byte w*128 + ((cb^(w&7))<<4) = x[b,h,w,cb*8..+8]
__global__ void prep_all(const float* __restrict__ x, const float* __restrict__ kr,
                         unsigned short* __restrict__ ws) {
  int bid = (int)blockIdx.x;
  if (bid < 72) {
    int t = bid * 256 + threadIdx.x;   // [0, 18432)
    int lane = t & 63;
    int kk   = (t >> 6) & 1;
    int cf   = (t >> 7) & 7;
    int rest = t >> 10;          // fi*9 + s
    int s  = rest % 9;
    int fi = rest / 9;
    int l15 = lane & 15, l4 = lane >> 4;
    int col = fi * 128 + cf * 16 + l15;
    int k0  = s * 64 + (kk * 4 + l4) * 8;
    unsigned short* dst = ws + (size_t)t * 8;
    const float* src = kr + (size_t)k0 * NF + col;
    #pragma unroll
    for (int e = 0; e < 8; ++e) dst[e] = f2b(src[(size_t)e * NF]);
  } else {
    int idx = (bid - 72) * 256 + threadIdx.x;   // [0, 2097152) 16B tasks
    int q   = idx & 1023;
    int row = idx >> 10;                        // b*128+h
    int w = q >> 3, cb = q & 7;
    const float* src = x + ((size_t)row * NW + w) * NC + cb * 8;
    float4 a0 = *(const float4*)(src);
    float4 a1 = *(const float4*)(src + 4);
    union { unsigned short u[8]; i32x4 v; } p;
    p.u[0] = f2b(a0.x); p.u[1] = f2b(a0.y); p.u[2] = f2b(a0.z); p.u[3] = f2b(a0.w);
    p.u[4] = f2b(a1.x); p.u[5] = f2b(a1.y); p.u[6] = f2b(a1.z); p.u[7] = f2b(a1.w);
    *(i32x4*)((char*)ws + XOFF + (size_t)row * SLOT + w * 128 + ((cb ^ (w & 7)) << 4)) = p.v;
  }
}

// conv: R8 structure at DOUBLE occupancy. Block = one (b,h) x half-N(128F),
// 512 threads = 8 waves (2 wm x 4 wn), wave tile 64w x 32F. VGPR <= 128 so
// 16 waves/CU (4/SIMD): 3 alternate waves per SIMD hide store/LDS stalls.
// A via DMA from pre-swizzled images; B register double-buffer; full-line
// epilogue; setprio(1) around MFMA cluster (independent-wave regime).
template<bool DMA_A>
__global__ __launch_bounds__(512, 4)
void conv_main(const float* __restrict__ x, const unsigned short* __restrict__ bt,
               const float* __restrict__ bias, float* __restrict__ out)
{
  __shared__ __align__(16) char lds[3 * SLOT];   // 48 KB; epilogue reuses

  const int tid  = threadIdx.x;
  const int lane = tid & 63;
  const int l15  = lane & 15;
  const int l4   = lane >> 4;
  const int wid  = tid >> 6;
  const int wm   = wid >> 2;    // 2: w-half
  const int wn   = wid & 3;     // 4: F-eighth (32 cols of this fi half)

  // XCD-aware bijective swizzle: nwg=4096, 512 per XCD.
  int bid  = (int)blockIdx.x;
  int work = (bid & 7) * 512 + (bid >> 3);
  int mi = work >> 1;           // (b,h) flat
  int fi = work & 1;
  int bb = mi >> 7;
  int hh = mi & 127;
  int F0 = fi * 128;

  const char* bimg = (const char*)bt + (size_t)fi * 9 * 16384;
  const int boff = wn * 4096 + lane * 16;   // frag n at +n*2048, kk at +kk*1024

  bf16x8 breg[2][2][2];   // [buf][n][kk] = 8 x bf16x8 = 32 VGPR

  // ---- prologue: B(0) -> buf0 ----
  #pragma unroll
  for (int n = 0; n < 2; ++n)
    #pragma unroll
    for (int kk = 0; kk < 2; ++kk)
      breg[0][n][kk] = *(const bf16x8*)(bimg + boff + n * 2048 + kk * 1024);

  // ---- stage A rows h-1,h,h+1 -> slots 0..2 ----
  if constexpr (DMA_A) {
    const char* xim = (const char*)bt + XOFF;
    #pragma unroll
    for (int r = 0; r < 3; ++r) {
      int xr = (hh + r + 127) & 127;
      const char* src = xim + ((size_t)(bb * NH + xr)) * SLOT;
      #pragma unroll
      for (int i = 0; i < 2; ++i) {
        int byte = tid * 16 + i * 8192;
        gload16(src + byte, lds + r * SLOT + byte);
      }
    }
  } else {
    #pragma unroll
    for (int i = 0; i < 6; ++i) {
      int idx = tid + i * 512;
      int cb = idx & 7;
      int w  = (idx >> 3) & 127;
      int r  = idx >> 10;
      int xr = (hh + r + 127) & 127;
      const float* src = x + (((size_t)(bb * NH + xr) * NW + w) * NC + cb * 8);
      float4 a0 = *(const float4*)(src);
      float4 a1 = *(const float4*)(src + 4);
      union { unsigned short u[8]; i32x4 v; } p;
      p.u[0] = f2b(a0.x); p.u[1] = f2b(a0.y); p.u[2] = f2b(a0.z); p.u[3] = f2b(a0.w);
      p.u[4] = f2b(a1.x); p.u[5] = f2b(a1.y); p.u[6] = f2b(a1.z); p.u[7] = f2b(a1.w);
      *(i32x4*)(lds + (r * SLOT + w * 128 + ((cb ^ (w & 7)) << 4))) = p.v;
    }
  }
  __syncthreads();    // drains DMA vmcnt + B0; A read-only hereafter

  // compressed A-address LUT (R10-verified):
  //   addr(m,dwi) = slotb + ((trow[dwi] + m*2048) & 16383) + swz[dwi]
  //   kk=1 address = kk=0 address XOR 64
  int trow[3], swz[3];
  #pragma unroll
  for (int dwi = 0; dwi < 3; ++dwi) {
    int t = l15 + 1 - dwi;
    trow[dwi] = ((wm * 64 + t) & 127) * 128;
    swz[dwi]  = (l4 ^ (t & 7)) << 4;
  }

  f32x4 acc[4][2];   // 32 VGPR
  #pragma unroll
  for (int m = 0; m < 4; ++m)
    #pragma unroll
    for (int n = 0; n < 2; ++n)
      acc[m][n] = (f32x4){0.f, 0.f, 0.f, 0.f};

  #pragma unroll
  for (int s = 0; s < 9; ++s) {
    if (s < 8) {  // depth-1 prefetch: B(s+1) -> other buffer
      const char* bs = bimg + (size_t)(s + 1) * 16384 + boff;
      #pragma unroll
      for (int n = 0; n < 2; ++n)
        #pragma unroll
        for (int kk = 0; kk < 2; ++kk)
          breg[(s + 1) & 1][n][kk] = *(const bf16x8*)(bs + n * 2048 + kk * 1024);
    }
    const int dwi   = s / 3;                  // static
    const int slotb = (2 - (s % 3)) * SLOT;   // static
    #pragma unroll
    for (int kk = 0; kk < 2; ++kk) {
      bf16x8 af[4];
      #pragma unroll
      for (int m = 0; m < 4; ++m) {
        int addr = slotb + ((trow[dwi] + m * 2048) & 16383) + swz[dwi];
        af[m] = *(const bf16x8*)(lds + (addr ^ (kk << 6)));
      }
      __builtin_amdgcn_s_setprio(1);
      #pragma unroll
      for (int m = 0; m < 4; ++m)
        #pragma unroll
        for (int n = 0; n < 2; ++n)
          acc[m][n] = __builtin_amdgcn_mfma_f32_16x16x32_bf16(
              af[m], breg[s & 1][n][kk], acc[m][n], 0, 0, 0);
      __builtin_amdgcn_s_setprio(0);
    }
  }

  // ---- epilogue: bias + FULL-LINE stores via LDS transpose ----
  float bv[2];
  #pragma unroll
  for (int n = 0; n < 2; ++n) bv[n] = bias[F0 + wn * 32 + n * 16 + l15];

  __syncthreads();
  float* eb = (float*)lds;              // [64][132] padded f32 tile (33.8 KB)

  #pragma unroll
  for (int chunk = 0; chunk < 2; ++chunk) {
    if (wm == chunk) {                  // owning 4 waves deposit acc+bias
      #pragma unroll
      for (int m = 0; m < 4; ++m)
        #pragma unroll
        for (int jj = 0; jj < 4; ++jj) {
          int r = m * 16 + l4 * 4 + jj;               // 0..63 chunk-local
          #pragma unroll
          for (int n = 0; n < 2; ++n)
            eb[r * 132 + wn * 32 + n * 16 + l15] = acc[m][n][jj] + bv[n];
        }
    }
    __syncthreads();
    // all 8 waves store: per instr 64 lanes x f32x4; 4 iters cover 64x128
    size_t obase = ((size_t)mi * 128 + chunk * 64) * NF + F0;
    #pragma unroll
    for (int i = 0; i < 4; ++i) {
      int r = i * 16 + (tid >> 5);          // 0..63
      int c = (tid & 31) * 4;               // 0..124
      f32x4 v = *(const f32x4*)(eb + r * 132 + c);
      *(f32x4*)(out + obase + (size_t)r * NF + c) = v;
    }
    if (chunk == 0) __syncthreads();    // before chunk 1 overwrites eb
  }
}

extern "C" void kernel_launch(void* const* d_in, const int* in_sizes, int n_in,
                              void* d_out, int out_size, void* d_ws, size_t ws_size,
                              hipStream_t stream) {
  const float* x    = (const float*)d_in[0];
  const float* kern = (const float*)d_in[1];
  const float* bias = (const float*)d_in[2];
  float* out = (float*)d_out;
  unsigned short* bt = (unsigned short*)d_ws;

  if (ws_size >= (size_t)WS_NEED) {
    prep_all<<<dim3(72 + 8192), dim3(256), 0, stream>>>(x, kern, bt);
    conv_main<true><<<dim3(4096), dim3(512), 0, stream>>>(x, bt, bias, out);
  } else {
    prep_all<<<dim3(72), dim3(256), 0, stream>>>(x, kern, bt);
    conv_main<false><<<dim3(4096), dim3(512), 0, stream>>>(x, bt, bias, out);
  }
}

// Round 14
// 102.567 us; speedup vs baseline: 1.7866x; 1.0877x over previous
//
#include <hip/hip_runtime.h>
#include <stdint.h>
#include <stddef.h>

typedef __attribute__((ext_vector_type(8))) short bf16x8;
typedef __attribute__((ext_vector_type(4))) float f32x4;
typedef __attribute__((ext_vector_type(4))) int i32x4;

#define NH 128
#define NW 128
#define NC 64
#define NF 256
#define SLOT 16384                 // one x-row image: [w=128][cb=8 x 16B], XOR-swizzled
#define XOFF 294912                // x images start here in ws (after 288 KB B table)
#define WS_NEED (XOFF + 2048 * SLOT)

__device__ __forceinline__ unsigned short f2b(float f) {
  union { float f; uint32_t u; } t; t.f = f;
  uint32_t u = t.u;
  return (unsigned short)((u + 0x7fffu + ((u >> 16) & 1u)) >> 16);
}

__device__ __forceinline__ void gload16(const void* g, void* l) {
  __builtin_amdgcn_global_load_lds(
      (const __attribute__((address_space(1))) unsigned int*)g,
      (__attribute__((address_space(3))) unsigned int*)l, 16, 0, 0);
}

// Combined prep (R8-verified, unchanged):
//  blocks [0,72):   B table in per-wave fragment order:
//    u16 elem ((fi*9+s)*16 + cf*2 + kk)*512 + lane*8 + e
//      = kern[(s*64 + (kk*4+(lane>>4))*8 + e)*NF + fi*128 + cf*16 + (lane&15)]
//  blocks [72,...): x -> bf16 swizzled 16KB row-images at XOFF:
//    image (b*128+h), byte w*128 + ((cb^(w&7))<<4) = x[b,h,w,cb*8..+8]
__global__ void prep_all(const float* __restrict__ x, const float* __restrict__ kr,
                         unsigned short* __restrict__ ws) {
  int bid = (int)blockIdx.x;
  if (bid < 72) {
    int t = bid * 256 + threadIdx.x;   // [0, 18432)
    int lane = t & 63;
    int kk   = (t >> 6) & 1;
    int cf   = (t >> 7) & 7;
    int rest = t >> 10;          // fi*9 + s
    int s  = rest % 9;
    int fi = rest / 9;
    int l15 = lane & 15, l4 = lane >> 4;
    int col = fi * 128 + cf * 16 + l15;
    int k0  = s * 64 + (kk * 4 + l4) * 8;
    unsigned short* dst = ws + (size_t)t * 8;
    const float* src = kr + (size_t)k0 * NF + col;
    #pragma unroll
    for (int e = 0; e < 8; ++e) dst[e] = f2b(src[(size_t)e * NF]);
  } else {
    int idx = (bid - 72) * 256 + threadIdx.x;   // [0, 2097152) 16B tasks
    int q   = idx & 1023;
    int row = idx >> 10;                        // b*128+h
    int w = q >> 3, cb = q & 7;
    const float* src = x + ((size_t)row * NW + w) * NC + cb * 8;
    float4 a0 = *(const float4*)(src);
    float4 a1 = *(const float4*)(src + 4);
    union { unsigned short u[8]; i32x4 v; } p;
    p.u[0] = f2b(a0.x); p.u[1] = f2b(a0.y); p.u[2] = f2b(a0.z); p.u[3] = f2b(a0.w);
    p.u[4] = f2b(a1.x); p.u[5] = f2b(a1.y); p.u[6] = f2b(a1.z); p.u[7] = f2b(a1.w);
    *(i32x4*)((char*)ws + XOFF + (size_t)row * SLOT + w * 128 + ((cb ^ (w & 7)) << 4)) = p.v;
  }
}

// conv: R13 structure (16 waves/CU) + NON-TEMPORAL output stores.
// Output lines are write-once/never-read: nt keeps them out of L2 so the
// x-images + B table stay resident (fixes the ~170 MB FETCH inflation and
// partial-line writeback inflation seen in R11's counters).
template<bool DMA_A>
__global__ __launch_bounds__(512, 4)
void conv_main(const float* __restrict__ x, const unsigned short* __restrict__ bt,
               const float* __restrict__ bias, float* __restrict__ out)
{
  __shared__ __align__(16) char lds[3 * SLOT];   // 48 KB; epilogue reuses

  const int tid  = threadIdx.x;
  const int lane = tid & 63;
  const int l15  = lane & 15;
  const int l4   = lane >> 4;
  const int wid  = tid >> 6;
  const int wm   = wid >> 2;    // 2: w-half
  const int wn   = wid & 3;     // 4: F-eighth (32 cols of this fi half)

  // XCD-aware bijective swizzle: nwg=4096, 512 per XCD.
  int bid  = (int)blockIdx.x;
  int work = (bid & 7) * 512 + (bid >> 3);
  int mi = work >> 1;           // (b,h) flat
  int fi = work & 1;
  int bb = mi >> 7;
  int hh = mi & 127;
  int F0 = fi * 128;

  const char* bimg = (const char*)bt + (size_t)fi * 9 * 16384;
  const int boff = wn * 4096 + lane * 16;   // frag n at +n*2048, kk at +kk*1024

  bf16x8 breg[2][2][2];   // [buf][n][kk] = 8 x bf16x8 = 32 VGPR

  // ---- prologue: B(0) -> buf0 ----
  #pragma unroll
  for (int n = 0; n < 2; ++n)
    #pragma unroll
    for (int kk = 0; kk < 2; ++kk)
      breg[0][n][kk] = *(const bf16x8*)(bimg + boff + n * 2048 + kk * 1024);

  // ---- stage A rows h-1,h,h+1 -> slots 0..2 ----
  if constexpr (DMA_A) {
    const char* xim = (const char*)bt + XOFF;
    #pragma unroll
    for (int r = 0; r < 3; ++r) {
      int xr = (hh + r + 127) & 127;
      const char* src = xim + ((size_t)(bb * NH + xr)) * SLOT;
      #pragma unroll
      for (int i = 0; i < 2; ++i) {
        int byte = tid * 16 + i * 8192;
        gload16(src + byte, lds + r * SLOT + byte);
      }
    }
  } else {
    #pragma unroll
    for (int i = 0; i < 6; ++i) {
      int idx = tid + i * 512;
      int cb = idx & 7;
      int w  = (idx >> 3) & 127;
      int r  = idx >> 10;
      int xr = (hh + r + 127) & 127;
      const float* src = x + (((size_t)(bb * NH + xr) * NW + w) * NC + cb * 8);
      float4 a0 = *(const float4*)(src);
      float4 a1 = *(const float4*)(src + 4);
      union { unsigned short u[8]; i32x4 v; } p;
      p.u[0] = f2b(a0.x); p.u[1] = f2b(a0.y); p.u[2] = f2b(a0.z); p.u[3] = f2b(a0.w);
      p.u[4] = f2b(a1.x); p.u[5] = f2b(a1.y); p.u[6] = f2b(a1.z); p.u[7] = f2b(a1.w);
      *(i32x4*)(lds + (r * SLOT + w * 128 + ((cb ^ (w & 7)) << 4))) = p.v;
    }
  }
  __syncthreads();    // drains DMA vmcnt + B0; A read-only hereafter

  // compressed A-address LUT (R10-verified):
  //   addr(m,dwi) = slotb + ((trow[dwi] + m*2048) & 16383) + swz[dwi]
  //   kk=1 address = kk=0 address XOR 64
  int trow[3], swz[3];
  #pragma unroll
  for (int dwi = 0; dwi < 3; ++dwi) {
    int t = l15 + 1 - dwi;
    trow[dwi] = ((wm * 64 + t) & 127) * 128;
    swz[dwi]  = (l4 ^ (t & 7)) << 4;
  }

  f32x4 acc[4][2];   // 32 VGPR
  #pragma unroll
  for (int m = 0; m < 4; ++m)
    #pragma unroll
    for (int n = 0; n < 2; ++n)
      acc[m][n] = (f32x4){0.f, 0.f, 0.f, 0.f};

  #pragma unroll
  for (int s = 0; s < 9; ++s) {
    if (s < 8) {  // depth-1 prefetch: B(s+1) -> other buffer
      const char* bs = bimg + (size_t)(s + 1) * 16384 + boff;
      #pragma unroll
      for (int n = 0; n < 2; ++n)
        #pragma unroll
        for (int kk = 0; kk < 2; ++kk)
          breg[(s + 1) & 1][n][kk] = *(const bf16x8*)(bs + n * 2048 + kk * 1024);
    }
    const int dwi   = s / 3;                  // static
    const int slotb = (2 - (s % 3)) * SLOT;   // static
    #pragma unroll
    for (int kk = 0; kk < 2; ++kk) {
      bf16x8 af[4];
      #pragma unroll
      for (int m = 0; m < 4; ++m) {
        int addr = slotb + ((trow[dwi] + m * 2048) & 16383) + swz[dwi];
        af[m] = *(const bf16x8*)(lds + (addr ^ (kk << 6)));
      }
      __builtin_amdgcn_s_setprio(1);
      #pragma unroll
      for (int m = 0; m < 4; ++m)
        #pragma unroll
        for (int n = 0; n < 2; ++n)
          acc[m][n] = __builtin_amdgcn_mfma_f32_16x16x32_bf16(
              af[m], breg[s & 1][n][kk], acc[m][n], 0, 0, 0);
      __builtin_amdgcn_s_setprio(0);
    }
  }

  // ---- epilogue: bias + FULL-LINE NON-TEMPORAL stores via LDS transpose ----
  float bv[2];
  #pragma unroll
  for (int n = 0; n < 2; ++n) bv[n] = bias[F0 + wn * 32 + n * 16 + l15];

  __syncthreads();
  float* eb = (float*)lds;              // [64][132] padded f32 tile (33.8 KB)

  #pragma unroll
  for (int chunk = 0; chunk < 2; ++chunk) {
    if (wm == chunk) {                  // owning 4 waves deposit acc+bias
      #pragma unroll
      for (int m = 0; m < 4; ++m)
        #pragma unroll
        for (int jj = 0; jj < 4; ++jj) {
          int r = m * 16 + l4 * 4 + jj;               // 0..63 chunk-local
          #pragma unroll
          for (int n = 0; n < 2; ++n)
            eb[r * 132 + wn * 32 + n * 16 + l15] = acc[m][n][jj] + bv[n];
        }
    }
    __syncthreads();
    // all 8 waves store: per instr 64 lanes x f32x4 = 1024B contiguous; nt
    size_t obase = ((size_t)mi * 128 + chunk * 64) * NF + F0;
    #pragma unroll
    for (int i = 0; i < 4; ++i) {
      int r = i * 16 + (tid >> 5);          // 0..63
      int c = (tid & 31) * 4;               // 0..124
      f32x4 v = *(const f32x4*)(eb + r * 132 + c);
      __builtin_nontemporal_store(v, (f32x4*)(out + obase + (size_t)r * NF + c));
    }
    if (chunk == 0) __syncthreads();    // before chunk 1 overwrites eb
  }
}

extern "C" void kernel_launch(void* const* d_in, const int* in_sizes, int n_in,
                              void* d_out, int out_size, void* d_ws, size_t ws_size,
                              hipStream_t stream) {
  const float* x    = (const float*)d_in[0];
  const float* kern = (const float*)d_in[1];
  const float* bias = (const float*)d_in[2];
  float* out = (float*)d_out;
  unsigned short* bt = (unsigned short*)d_ws;

  if (ws_size >= (size_t)WS_NEED) {
    prep_all<<<dim3(72 + 8192), dim3(256), 0, stream>>>(x, kern, bt);
    conv_main<true><<<dim3(4096), dim3(512), 0, stream>>>(x, bt, bias, out);
  } else {
    prep_all<<<dim3(72), dim3(256), 0, stream>>>(x, kern, bt);
    conv_main<false><<<dim3(4096), dim3(512), 0, stream>>>(x, bt, bias, out);
  }
}

// Round 15
// 102.433 us; speedup vs baseline: 1.7889x; 1.0013x over previous
//
#include <hip/hip_runtime.h>
#include <stdint.h>
#include <stddef.h>

typedef __attribute__((ext_vector_type(8))) short bf16x8;
typedef __attribute__((ext_vector_type(4))) float f32x4;
typedef __attribute__((ext_vector_type(4))) int i32x4;

#define NH 128
#define NW 128
#define NC 64
#define NF 256
#define SLOT 16384                 // one x-row tile in LDS: [w=128][cb=8 x 16B], XOR-swizzled

__device__ __forceinline__ unsigned short f2b(float f) {
  union { float f; uint32_t u; } t; t.f = f;
  uint32_t u = t.u;
  return (unsigned short)((u + 0x7fffu + ((u >> 16) & 1u)) >> 16);
}

// prep: B table only (72 blocks, ~3 us). Per-wave fragment order (R8-verified):
//   u16 elem ((fi*9+s)*16 + cf*2 + kk)*512 + lane*8 + e
//     = kern[(s*64 + (kk*4+(lane>>4))*8 + e)*NF + fi*128 + cf*16 + (lane&15)]
__global__ void prep_bt(const float* __restrict__ kr, unsigned short* __restrict__ ws) {
  int t = blockIdx.x * 256 + threadIdx.x;   // [0, 18432)
  int lane = t & 63;
  int kk   = (t >> 6) & 1;
  int cf   = (t >> 7) & 7;
  int rest = t >> 10;          // fi*9 + s
  int s  = rest % 9;
  int fi = rest / 9;
  int l15 = lane & 15, l4 = lane >> 4;
  int col = fi * 128 + cf * 16 + l15;
  int k0  = s * 64 + (kk * 4 + l4) * 8;
  unsigned short* dst = ws + (size_t)t * 8;
  const float* src = kr + (size_t)k0 * NF + col;
  #pragma unroll
  for (int e = 0; e < 8; ++e) dst[e] = f2b(src[(size_t)e * NF]);
}

// conv: R14 structure (16 waves/CU, NT full-line stores, setprio) with the
// f32->bf16 cast folded into A-staging (no x-image prep pass: total HBM
// 67+268 MB and zero serial dependency ahead of conv except the B table).
__global__ __launch_bounds__(512, 4)
void conv_main(const float* __restrict__ x, const unsigned short* __restrict__ bt,
               const float* __restrict__ bias, float* __restrict__ out)
{
  __shared__ __align__(16) char lds[3 * SLOT];   // 48 KB; epilogue reuses

  const int tid  = threadIdx.x;
  const int lane = tid & 63;
  const int l15  = lane & 15;
  const int l4   = lane >> 4;
  const int wid  = tid >> 6;
  const int wm   = wid >> 2;    // 2: w-half
  const int wn   = wid & 3;     // 4: F-eighth (32 cols of this fi half)

  // XCD-aware bijective swizzle: nwg=4096, 512 per XCD; fi-pairs adjacent,
  // consecutive mi on one XCD -> x rows L2-shared across 6 readers.
  int bid  = (int)blockIdx.x;
  int work = (bid & 7) * 512 + (bid >> 3);
  int mi = work >> 1;           // (b,h) flat
  int fi = work & 1;
  int bb = mi >> 7;
  int hh = mi & 127;
  int F0 = fi * 128;

  const char* bimg = (const char*)bt + (size_t)fi * 9 * 16384;
  const int boff = wn * 4096 + lane * 16;   // frag n at +n*2048, kk at +kk*1024

  bf16x8 breg[2][2][2];   // [buf][n][kk] = 32 VGPR

  // ---- prologue: B(0) -> buf0 (issues first, flies under staging VALU) ----
  #pragma unroll
  for (int n = 0; n < 2; ++n)
    #pragma unroll
    for (int kk = 0; kk < 2; ++kk)
      breg[0][n][kk] = *(const bf16x8*)(bimg + boff + n * 2048 + kk * 1024);

  // ---- stage A rows h-1,h,h+1 -> slots 0..2 (cast in-kernel) ----
  #pragma unroll
  for (int i = 0; i < 6; ++i) {
    int idx = tid + i * 512;            // 3072 16B-blocks (3 rows)
    int cb = idx & 7;
    int w  = (idx >> 3) & 127;
    int r  = idx >> 10;                 // 0..2
    int xr = (hh + r + 127) & 127;
    const float* src = x + (((size_t)(bb * NH + xr) * NW + w) * NC + cb * 8);
    float4 a0 = *(const float4*)(src);
    float4 a1 = *(const float4*)(src + 4);
    union { unsigned short u[8]; i32x4 v; } p;
    p.u[0] = f2b(a0.x); p.u[1] = f2b(a0.y); p.u[2] = f2b(a0.z); p.u[3] = f2b(a0.w);
    p.u[4] = f2b(a1.x); p.u[5] = f2b(a1.y); p.u[6] = f2b(a1.z); p.u[7] = f2b(a1.w);
    *(i32x4*)(lds + (r * SLOT + w * 128 + ((cb ^ (w & 7)) << 4))) = p.v;
  }
  __syncthreads();    // A staged; read-only hereafter

  // compressed A-address LUT (R10-verified):
  //   addr(m,dwi) = slotb + ((trow[dwi] + m*2048) & 16383) + swz[dwi]
  //   kk=1 address = kk=0 address XOR 64
  int trow[3], swz[3];
  #pragma unroll
  for (int dwi = 0; dwi < 3; ++dwi) {
    int t = l15 + 1 - dwi;
    trow[dwi] = ((wm * 64 + t) & 127) * 128;
    swz[dwi]  = (l4 ^ (t & 7)) << 4;
  }

  f32x4 acc[4][2];   // 32 VGPR
  #pragma unroll
  for (int m = 0; m < 4; ++m)
    #pragma unroll
    for (int n = 0; n < 2; ++n)
      acc[m][n] = (f32x4){0.f, 0.f, 0.f, 0.f};

  #pragma unroll
  for (int s = 0; s < 9; ++s) {
    if (s < 8) {  // depth-1 B prefetch -> other buffer
      const char* bs = bimg + (size_t)(s + 1) * 16384 + boff;
      #pragma unroll
      for (int n = 0; n < 2; ++n)
        #pragma unroll
        for (int kk = 0; kk < 2; ++kk)
          breg[(s + 1) & 1][n][kk] = *(const bf16x8*)(bs + n * 2048 + kk * 1024);
    }
    const int dwi   = s / 3;                  // static
    const int slotb = (2 - (s % 3)) * SLOT;   // static
    #pragma unroll
    for (int kk = 0; kk < 2; ++kk) {
      bf16x8 af[4];
      #pragma unroll
      for (int m = 0; m < 4; ++m) {
        int addr = slotb + ((trow[dwi] + m * 2048) & 16383) + swz[dwi];
        af[m] = *(const bf16x8*)(lds + (addr ^ (kk << 6)));
      }
      __builtin_amdgcn_s_setprio(1);
      #pragma unroll
      for (int m = 0; m < 4; ++m)
        #pragma unroll
        for (int n = 0; n < 2; ++n)
          acc[m][n] = __builtin_amdgcn_mfma_f32_16x16x32_bf16(
              af[m], breg[s & 1][n][kk], acc[m][n], 0, 0, 0);
      __builtin_amdgcn_s_setprio(0);
    }
  }

  // ---- epilogue: bias + FULL-LINE NON-TEMPORAL stores via LDS transpose ----
  float bv[2];
  #pragma unroll
  for (int n = 0; n < 2; ++n) bv[n] = bias[F0 + wn * 32 + n * 16 + l15];

  __syncthreads();
  float* eb = (float*)lds;              // [64][132] padded f32 tile (33.8 KB)

  #pragma unroll
  for (int chunk = 0; chunk < 2; ++chunk) {
    if (wm == chunk) {                  // owning 4 waves deposit acc+bias
      #pragma unroll
      for (int m = 0; m < 4; ++m)
        #pragma unroll
        for (int jj = 0; jj < 4; ++jj) {
          int r = m * 16 + l4 * 4 + jj;               // 0..63 chunk-local
          #pragma unroll
          for (int n = 0; n < 2; ++n)
            eb[r * 132 + wn * 32 + n * 16 + l15] = acc[m][n][jj] + bv[n];
        }
    }
    __syncthreads();
    // all 8 waves: per instr 64 lanes x f32x4 = 1024B contiguous; NT
    size_t obase = ((size_t)mi * 128 + chunk * 64) * NF + F0;
    #pragma unroll
    for (int i = 0; i < 4; ++i) {
      int r = i * 16 + (tid >> 5);          // 0..63
      int c = (tid & 31) * 4;               // 0..124
      f32x4 v = *(const f32x4*)(eb + r * 132 + c);
      __builtin_nontemporal_store(v, (f32x4*)(out + obase + (size_t)r * NF + c));
    }
    if (chunk == 0) __syncthreads();    // before chunk 1 overwrites eb
  }
}

extern "C" void kernel_launch(void* const* d_in, const int* in_sizes, int n_in,
                              void* d_out, int out_size, void* d_ws, size_t ws_size,
                              hipStream_t stream) {
  const float* x    = (const float*)d_in[0];
  const float* kern = (const float*)d_in[1];
  const float* bias = (const float*)d_in[2];
  float* out = (float*)d_out;
  unsigned short* bt = (unsigned short*)d_ws;   // 294912 bytes

  prep_bt<<<dim3(72), dim3(256), 0, stream>>>(kern, bt);
  conv_main<<<dim3(4096), dim3(512), 0, stream>>>(x, bt, bias, out);
}